// Round 1
// baseline (179.134 us; speedup 1.0000x reference)
//
#include <hip/hip_runtime.h>
#include <hip/hip_bf16.h>

#define B_ 2
#define R_ 1
#define A_ 16
#define S_ 14
#define F_ 1024
#define N_ 512
#define D_ (S_*N_)        // 7168
#define M_ (B_*R_*A_)     // 32
#define KK_ (2*D_)        // 14336
#define KSPLIT 8
#define KBLK (KK_/KSPLIT) // 1792
#define BE 64
#define ETILES (D_/BE)    // 112

typedef __attribute__((ext_vector_type(8))) short bf16x8;
typedef __attribute__((ext_vector_type(4))) float f32x4;

static __device__ inline short f2bf(float f) {
    __hip_bfloat16 h = __float2bfloat16(f);
    return *reinterpret_cast<short*>(&h);
}

// Build packed A' [64][14336] bf16:
//   rows 0..31 : [ yr | yi ]
//   rows 32..63: [ yi | -yr ]
// where y[m, s*512+n] = x[m, s, sc[n]]
__global__ void prep_kernel(const float* __restrict__ xr, const float* __restrict__ xi,
                            const int* __restrict__ sc, short* __restrict__ Ap) {
    int idx = blockIdx.x * blockDim.x + threadIdx.x;
    if (idx >= 64 * KK_) return;
    int k = idx % KK_;
    int r = idx / KK_;
    int m = r & 31;
    int half = (k >= D_) ? 1 : 0;
    int d = half ? (k - D_) : k;
    int s = d >> 9;       // /512
    int n = d & 511;
    int f = sc[n];
    const float* base = (r < 32) ? (half ? xi : xr)
                                 : (half ? xr : xi);
    float v = base[(m * S_ + s) * F_ + f];
    if (r >= 32 && half) v = -v;
    Ap[idx] = f2bf(v);
}

__global__ void zero_kernel(float4* __restrict__ out, int n4) {
    int i = blockIdx.x * blockDim.x + threadIdx.x;
    if (i < n4) out[i] = make_float4(0.f, 0.f, 0.f, 0.f);
}

// out = A'[64 x 14336] * Bpack^T, Bpack[e][k] = (k<7168) ? Cre[e][k] : Cim[e][k-7168]
// grid (112 e-tiles, 8 k-splits), 256 threads (4 waves, 16 cols each), M=64 per block.
template<int PARTIALS>
__global__ __launch_bounds__(256) void gemm_kernel(
    const short* __restrict__ Ap,
    const float* __restrict__ Cre, const float* __restrict__ Cim,
    const int* __restrict__ sc,
    float* __restrict__ outp)
{
    const int etile = blockIdx.x;   // 0..111
    const int ks    = blockIdx.y;   // 0..7
    const int tid   = threadIdx.x;
    const int wave  = tid >> 6;
    const int lane  = tid & 63;
    const int l16   = lane & 15;
    const int kg    = lane >> 4;

    const int e_lane = etile * BE + wave * 16 + l16;    // output column = C row
    const float* Cp  = (ks < KSPLIT/2) ? Cre : Cim;
    const int kc = (ks & (KSPLIT/2 - 1)) * KBLK;        // column base in C
    const int ka = ks * KBLK;                           // k base in packed A'

    const float* crow  = Cp + (size_t)e_lane * D_ + kc + kg * 8;
    const short* abase = Ap + (size_t)l16 * KK_ + ka + kg * 8;

    f32x4 acc0 = {0.f,0.f,0.f,0.f}, acc1 = {0.f,0.f,0.f,0.f};
    f32x4 acc2 = {0.f,0.f,0.f,0.f}, acc3 = {0.f,0.f,0.f,0.f};

    #pragma unroll 2
    for (int kk = 0; kk < KBLK; kk += 32) {
        // B fragment: 8 consecutive f32 of this lane's C row -> bf16
        f32x4 b0 = *reinterpret_cast<const f32x4*>(crow + kk);
        f32x4 b1 = *reinterpret_cast<const f32x4*>(crow + kk + 4);
        bf16x8 bf;
        bf[0] = f2bf(b0.x); bf[1] = f2bf(b0.y); bf[2] = f2bf(b0.z); bf[3] = f2bf(b0.w);
        bf[4] = f2bf(b1.x); bf[5] = f2bf(b1.y); bf[6] = f2bf(b1.z); bf[7] = f2bf(b1.w);
        // A fragments (4 row-tiles of 16)
        bf16x8 a0 = *reinterpret_cast<const bf16x8*>(abase + kk);
        bf16x8 a1 = *reinterpret_cast<const bf16x8*>(abase + (size_t)16 * KK_ + kk);
        bf16x8 a2 = *reinterpret_cast<const bf16x8*>(abase + (size_t)32 * KK_ + kk);
        bf16x8 a3 = *reinterpret_cast<const bf16x8*>(abase + (size_t)48 * KK_ + kk);
        acc0 = __builtin_amdgcn_mfma_f32_16x16x32_bf16(a0, bf, acc0, 0, 0, 0);
        acc1 = __builtin_amdgcn_mfma_f32_16x16x32_bf16(a1, bf, acc1, 0, 0, 0);
        acc2 = __builtin_amdgcn_mfma_f32_16x16x32_bf16(a2, bf, acc2, 0, 0, 0);
        acc3 = __builtin_amdgcn_mfma_f32_16x16x32_bf16(a3, bf, acc3, 0, 0, 0);
    }

    if (PARTIALS) {
        // partials[ks][64][7168]
        float* p = outp + (size_t)ks * (64 * D_);
        #pragma unroll
        for (int mt = 0; mt < 4; ++mt) {
            f32x4 a = (mt == 0) ? acc0 : (mt == 1) ? acc1 : (mt == 2) ? acc2 : acc3;
            int rbase = mt * 16 + kg * 4;   // D-frag: row=(lane>>4)*4+reg, col=lane&15
            #pragma unroll
            for (int r = 0; r < 4; ++r)
                p[(size_t)(rbase + r) * D_ + e_lane] = a[r];
        }
    } else {
        int s = e_lane >> 9, n = e_lane & 511;
        int f = sc[n];
        #pragma unroll
        for (int mt = 0; mt < 4; ++mt) {
            f32x4 a = (mt == 0) ? acc0 : (mt == 1) ? acc1 : (mt == 2) ? acc2 : acc3;
            int rbase = mt * 16 + kg * 4;
            #pragma unroll
            for (int r = 0; r < 4; ++r) {
                int rr = rbase + r;
                int pp = rr >> 5, m = rr & 31;
                atomicAdd(&outp[((pp * M_ + m) * S_ + s) * F_ + f], a[r]);
            }
        }
    }
}

// Sum 8 K-split partials, scatter into [2,B,R,A,S,F] at f = sc[n]
__global__ void reduce_kernel(const float* __restrict__ part, const int* __restrict__ sc,
                              float* __restrict__ out) {
    int idx = blockIdx.x * blockDim.x + threadIdx.x;  // 64*7168
    if (idx >= 64 * D_) return;
    int e = idx % D_;
    int r = idx / D_;
    float v = 0.f;
    #pragma unroll
    for (int ks = 0; ks < KSPLIT; ++ks)
        v += part[(size_t)ks * (64 * D_) + idx];
    int pp = r >> 5, m = r & 31, s = e >> 9, n = e & 511;
    int f = sc[n];
    out[((pp * M_ + m) * S_ + s) * F_ + f] = v;
}

extern "C" void kernel_launch(void* const* d_in, const int* in_sizes, int n_in,
                              void* d_out, int out_size, void* d_ws, size_t ws_size,
                              hipStream_t stream) {
    const float* xr  = (const float*)d_in[0];
    const float* xi  = (const float*)d_in[1];
    const float* Cre = (const float*)d_in[2];
    const float* Cim = (const float*)d_in[3];
    const int*   sc  = (const int*)d_in[4];
    float* out = (float*)d_out;

    short* Ap = (short*)d_ws;
    const size_t partOff   = 2u * 1024u * 1024u;                 // A' uses first 1.84 MB
    const size_t partBytes = (size_t)KSPLIT * 64 * D_ * 4;       // 14.68 MB
    const bool use_partials = ws_size >= partOff + partBytes;

    prep_kernel<<<dim3((64 * KK_ + 255) / 256), 256, 0, stream>>>(xr, xi, sc, Ap);
    zero_kernel<<<dim3((917504 / 4 + 255) / 256), 256, 0, stream>>>((float4*)out, 917504 / 4);

    if (use_partials) {
        float* part = (float*)((char*)d_ws + partOff);
        gemm_kernel<1><<<dim3(ETILES, KSPLIT), 256, 0, stream>>>(Ap, Cre, Cim, sc, part);
        reduce_kernel<<<dim3((64 * D_ + 255) / 256), 256, 0, stream>>>(part, sc, out);
    } else {
        gemm_kernel<0><<<dim3(ETILES, KSPLIT), 256, 0, stream>>>(Ap, Cre, Cim, sc, out);
    }
}

// Round 2
// 116.209 us; speedup vs baseline: 1.5415x; 1.5415x over previous
//
#include <hip/hip_runtime.h>
#include <hip/hip_bf16.h>

#define B_ 2
#define R_ 1
#define A_ 16
#define S_ 14
#define F_ 1024
#define N_ 512
#define D_ (S_*N_)        // 7168
#define M_ (B_*R_*A_)     // 32
#define KK_ (2*D_)        // 14336
#define BE 64
#define ETILES (D_/BE)    // 112

typedef __attribute__((ext_vector_type(8))) short bf16x8;
typedef __attribute__((ext_vector_type(4))) float f32x4;

static __device__ inline short f2bf(float f) {
    __hip_bfloat16 h = __float2bfloat16(f);
    return *reinterpret_cast<short*>(&h);
}
static __device__ inline float bf2f(short s) {
    unsigned int u = ((unsigned int)(unsigned short)s) << 16;
    return __uint_as_float(u);
}

#define LDSP(p) ((__attribute__((address_space(3))) void*)(p))
#define GLBP(p) ((const __attribute__((address_space(1))) void*)(p))

// Build packed A' [64][14336] bf16: rows 0..31: [yr|yi], rows 32..63: [yi|-yr]
__global__ void prep_kernel(const float* __restrict__ xr, const float* __restrict__ xi,
                            const int* __restrict__ sc, short* __restrict__ Ap) {
    int idx = blockIdx.x * blockDim.x + threadIdx.x;
    if (idx >= 64 * KK_) return;
    int k = idx % KK_;
    int r = idx / KK_;
    int m = r & 31;
    int half = (k >= D_) ? 1 : 0;
    int d = half ? (k - D_) : k;
    int s = d >> 9;
    int n = d & 511;
    int f = sc[n];
    const float* base = (r < 32) ? (half ? xi : xr) : (half ? xr : xi);
    float v = base[(m * S_ + s) * F_ + f];
    if (r >= 32 && half) v = -v;
    Ap[idx] = f2bf(v);
}

__global__ void zero_kernel(float4* __restrict__ out, int n4) {
    int i = blockIdx.x * blockDim.x + threadIdx.x;
    if (i < n4) out[i] = make_float4(0.f, 0.f, 0.f, 0.f);
}

// C-half GEMM with LDS staging (global_load_lds w16, double-buffered).
// Output col = e (C row), output row = packed-A row (64 of them).
template<int KSPLIT, int PARTIALS>
__global__ __launch_bounds__(256) void gemm_kernel(
    const short* __restrict__ Ap,
    const float* __restrict__ Cre, const float* __restrict__ Cim,
    const int* __restrict__ sc,
    void* __restrict__ outp)
{
    constexpr int KBLK = KK_ / KSPLIT;   // k per block (within one C half)
    constexpr int NCH  = KBLK / 32;      // 32-k chunks
    __shared__ float Bl[2][64 * 32];     // 8 KB per buf: C tile f32, swizzled
    __shared__ short Al[2][64 * 32];     // 4 KB per buf: A' tile bf16, linear

    const int etile = blockIdx.x;        // 0..111
    const int ks    = blockIdx.y;        // 0..KSPLIT-1
    const int tid   = threadIdx.x;
    const int wave  = tid >> 6;
    const int lane  = tid & 63;
    const int l16   = lane & 15;
    const int kg    = lane >> 4;

    const float* Cp = (ks < KSPLIT / 2) ? Cre : Cim;
    const int kc = (ks % (KSPLIT / 2)) * KBLK;   // col base within C half
    const int ka = ks * KBLK;                    // k base in packed A'

    // --- precomputed staging source addresses ---
    // B: thread stages 2x16B. LDS unit U = q*256+tid -> (row = U>>3, u' = U&7),
    // swizzle u = u' ^ (row&7) -> source floats p*8 + h*4 (p=u>>1, h=u&1).
    const float* bsrc[2];
    #pragma unroll
    for (int q = 0; q < 2; ++q) {
        int U = q * 256 + tid;
        int row = U >> 3;
        int u = (U & 7) ^ (row & 7);
        int p = u >> 1, h = u & 1;
        bsrc[q] = Cp + (size_t)(etile * 64 + row) * D_ + kc + p * 8 + h * 4;
    }
    // A: thread stages 1x16B: row = tid>>2 (m-row), unit = tid&3 (8 bf16 each)
    const short* asrc = Ap + (size_t)(tid >> 2) * KK_ + ka + (tid & 3) * 8;

    // stage chunk 0
    {
        #pragma unroll
        for (int q = 0; q < 2; ++q)
            __builtin_amdgcn_global_load_lds(GLBP(bsrc[q]), LDSP(&Bl[0][(q * 256 + tid) * 4]), 16, 0, 0);
        __builtin_amdgcn_global_load_lds(GLBP(asrc), LDSP(&Al[0][tid * 8]), 16, 0, 0);
    }
    __syncthreads();

    f32x4 acc0 = {0.f,0.f,0.f,0.f}, acc1 = {0.f,0.f,0.f,0.f};
    f32x4 acc2 = {0.f,0.f,0.f,0.f}, acc3 = {0.f,0.f,0.f,0.f};

    const int row = wave * 16 + l16;          // e within block tile
    const int swz = row & 7;
    const int boff = row * 32;                // float index of row base in Bl
    const int u0 = ((kg * 2 + 0) ^ swz) * 4;
    const int u1 = ((kg * 2 + 1) ^ swz) * 4;

    for (int c = 0; c < NCH; ++c) {
        const int cur = c & 1;
        const int nxt = cur ^ 1;
        if (c + 1 < NCH) {
            #pragma unroll
            for (int q = 0; q < 2; ++q)
                __builtin_amdgcn_global_load_lds(GLBP(bsrc[q] + (c + 1) * 32),
                                                 LDSP(&Bl[nxt][(q * 256 + tid) * 4]), 16, 0, 0);
            __builtin_amdgcn_global_load_lds(GLBP(asrc + (c + 1) * 32),
                                             LDSP(&Al[nxt][tid * 8]), 16, 0, 0);
        }
        // B fragment: 8 floats (k = kg*8 + 0..7) -> bf16
        f32x4 b0 = *reinterpret_cast<const f32x4*>(&Bl[cur][boff + u0]);
        f32x4 b1 = *reinterpret_cast<const f32x4*>(&Bl[cur][boff + u1]);
        bf16x8 bf;
        bf[0] = f2bf(b0.x); bf[1] = f2bf(b0.y); bf[2] = f2bf(b0.z); bf[3] = f2bf(b0.w);
        bf[4] = f2bf(b1.x); bf[5] = f2bf(b1.y); bf[6] = f2bf(b1.z); bf[7] = f2bf(b1.w);
        // A fragments: 4 m-tiles of 16 rows
        bf16x8 a0 = *reinterpret_cast<const bf16x8*>(&Al[cur][(0 * 16 + l16) * 32 + kg * 8]);
        bf16x8 a1 = *reinterpret_cast<const bf16x8*>(&Al[cur][(1 * 16 + l16) * 32 + kg * 8]);
        bf16x8 a2 = *reinterpret_cast<const bf16x8*>(&Al[cur][(2 * 16 + l16) * 32 + kg * 8]);
        bf16x8 a3 = *reinterpret_cast<const bf16x8*>(&Al[cur][(3 * 16 + l16) * 32 + kg * 8]);
        acc0 = __builtin_amdgcn_mfma_f32_16x16x32_bf16(a0, bf, acc0, 0, 0, 0);
        acc1 = __builtin_amdgcn_mfma_f32_16x16x32_bf16(a1, bf, acc1, 0, 0, 0);
        acc2 = __builtin_amdgcn_mfma_f32_16x16x32_bf16(a2, bf, acc2, 0, 0, 0);
        acc3 = __builtin_amdgcn_mfma_f32_16x16x32_bf16(a3, bf, acc3, 0, 0, 0);
        __syncthreads();
    }

    const int e_lane = etile * 64 + row;
    if (PARTIALS) {
        short* part = (short*)outp + (size_t)ks * (64 * D_);
        #pragma unroll
        for (int mt = 0; mt < 4; ++mt) {
            f32x4 a = (mt == 0) ? acc0 : (mt == 1) ? acc1 : (mt == 2) ? acc2 : acc3;
            int rbase = mt * 16 + kg * 4;    // D-frag: row=(lane>>4)*4+reg, col=lane&15
            #pragma unroll
            for (int r = 0; r < 4; ++r)
                part[(size_t)(rbase + r) * D_ + e_lane] = f2bf(a[r]);
        }
    } else {
        float* out = (float*)outp;
        int s = e_lane >> 9, n = e_lane & 511;
        int f = sc[n];
        #pragma unroll
        for (int mt = 0; mt < 4; ++mt) {
            f32x4 a = (mt == 0) ? acc0 : (mt == 1) ? acc1 : (mt == 2) ? acc2 : acc3;
            int rbase = mt * 16 + kg * 4;
            #pragma unroll
            for (int r = 0; r < 4; ++r) {
                int rr = rbase + r;
                int pp = rr >> 5, m = rr & 31;
                atomicAdd(&out[((pp * M_ + m) * S_ + s) * F_ + f], a[r]);
            }
        }
    }
}

// Sum KSPLIT bf16 partials (8 e-elements per thread), scatter into [2,B,R,A,S,F]
template<int KSPLIT>
__global__ void reduce_kernel(const short* __restrict__ part, const int* __restrict__ sc,
                              float* __restrict__ out) {
    int t = blockIdx.x * blockDim.x + threadIdx.x;
    if (t >= 64 * D_ / 8) return;
    int base = t * 8;
    int e0 = base % D_;
    int r  = base / D_;
    float v[8] = {0.f,0.f,0.f,0.f,0.f,0.f,0.f,0.f};
    #pragma unroll
    for (int ksp = 0; ksp < KSPLIT; ++ksp) {
        bf16x8 x = *reinterpret_cast<const bf16x8*>(&part[(size_t)ksp * (64 * D_) + base]);
        #pragma unroll
        for (int j = 0; j < 8; ++j) v[j] += bf2f(x[j]);
    }
    int pp = r >> 5, m = r & 31, s = e0 >> 9, n0 = e0 & 511;
    float* ob = &out[((pp * M_ + m) * S_ + s) * F_];
    #pragma unroll
    for (int j = 0; j < 8; ++j) ob[sc[n0 + j]] = v[j];
}

extern "C" void kernel_launch(void* const* d_in, const int* in_sizes, int n_in,
                              void* d_out, int out_size, void* d_ws, size_t ws_size,
                              hipStream_t stream) {
    const float* xr  = (const float*)d_in[0];
    const float* xi  = (const float*)d_in[1];
    const float* Cre = (const float*)d_in[2];
    const float* Cim = (const float*)d_in[3];
    const int*   sc  = (const int*)d_in[4];
    float* out = (float*)d_out;

    short* Ap = (short*)d_ws;
    const size_t partOff = 2u * 1024u * 1024u;
    const size_t need28  = partOff + 28ull * 64 * D_ * 2;
    const size_t need16  = partOff + 16ull * 64 * D_ * 2;

    prep_kernel<<<dim3((64 * KK_ + 255) / 256), 256, 0, stream>>>(xr, xi, sc, Ap);
    zero_kernel<<<dim3((917504 / 4 + 255) / 256), 256, 0, stream>>>((float4*)out, 917504 / 4);

    const int rthreads = 64 * D_ / 8;
    if (ws_size >= need28) {
        short* part = (short*)((char*)d_ws + partOff);
        gemm_kernel<28, 1><<<dim3(ETILES, 28), 256, 0, stream>>>(Ap, Cre, Cim, sc, part);
        reduce_kernel<28><<<dim3((rthreads + 255) / 256), 256, 0, stream>>>(part, sc, out);
    } else if (ws_size >= need16) {
        short* part = (short*)((char*)d_ws + partOff);
        gemm_kernel<16, 1><<<dim3(ETILES, 16), 256, 0, stream>>>(Ap, Cre, Cim, sc, part);
        reduce_kernel<16><<<dim3((rthreads + 255) / 256), 256, 0, stream>>>(part, sc, out);
    } else {
        gemm_kernel<16, 0><<<dim3(ETILES, 16), 256, 0, stream>>>(Ap, Cre, Cim, sc, out);
    }
}